// Round 9
// baseline (88.968 us; speedup 1.0000x reference)
//
#include <hip/hip_runtime.h>

#define HIST_BINS 2048             // 2^11 bins: top-11 bits of monotonic key
#define HIST_BYTES (HIST_BINS * 4)
#define KEY_SHIFT 21
#define NPART 16                   // partial global histograms
#define RECALL_LO_C 0.95
#define GRID_CE   2048             // no LDS -> 32 waves/CU possible
#define GRID_HIST 2048             // 8 KB LDS -> 8 blocks/CU fits easily

// ---------------------------------------------------------------------------
// Kernel A: CE partial sum + positive count. Pure streaming reduce, simple
// float4 grid-stride at full occupancy. Diagnostic: measures achievable
// stream rate of this load pattern in isolation.
// ---------------------------------------------------------------------------
__global__ __launch_bounds__(256) void ce_kernel(
    const float* __restrict__ pred, const int* __restrict__ tgt,
    double* __restrict__ ce_sum, unsigned int* __restrict__ pos_cnt, int n)
{
    float ce = 0.0f;
    unsigned int pc = 0;

    const int tid    = blockIdx.x * blockDim.x + threadIdx.x;
    const int stride = gridDim.x * blockDim.x;
    const int n4     = n >> 2;

    const float4* p4 = (const float4*)pred;
    const int4*   t4 = (const int4*)tgt;

    for (int i = tid; i < n4; i += stride) {
        float4 x = p4[i];
        int4   t = t4[i];
        float xs[4] = {x.x, x.y, x.z, x.w};
        int   ts[4] = {t.x, t.y, t.z, t.w};
#pragma unroll
        for (int c = 0; c < 4; ++c) {
            float xv = xs[c];
            ce += fmaxf(xv, 0.0f) - xv * (float)ts[c]
                + __logf(1.0f + __expf(-fabsf(xv)));
            pc += (unsigned int)ts[c];
        }
    }
    for (int i = (n4 << 2) + tid; i < n; i += stride) {
        float xv = pred[i];
        int   ti = tgt[i];
        ce += fmaxf(xv, 0.0f) - xv * (float)ti
            + __logf(1.0f + __expf(-fabsf(xv)));
        pc += (unsigned int)ti;
    }

    // wave reduce -> LDS -> one atomic pair per block
    for (int off = 32; off > 0; off >>= 1) {
        ce += __shfl_down(ce, off);
        pc += __shfl_down(pc, off);
    }
    __shared__ float        lce[4];
    __shared__ unsigned int lpc[4];
    const int wid = threadIdx.x >> 6;
    if ((threadIdx.x & 63) == 0) { lce[wid] = ce; lpc[wid] = pc; }
    __syncthreads();
    if (threadIdx.x == 0) {
        atomicAdd(ce_sum, (double)(lce[0] + lce[1] + lce[2] + lce[3]));
        atomicAdd(pos_cnt, lpc[0] + lpc[1] + lpc[2] + lpc[3]);
    }
}

// ---------------------------------------------------------------------------
// Kernel B: histogram only. Simple float4 grid-stride, LDS-privatized
// 2^11-bin packed histogram ([pos<<16 | neg]), NPART-partial flush.
// Per-block elements = N/2048 = 4096 -> no packed overflow in LDS; partial
// per-class sums <= ~20k < 65535; final sums unpacked in pass2.
// ---------------------------------------------------------------------------
__global__ __launch_bounds__(256) void hist_kernel(
    const float* __restrict__ pred, const int* __restrict__ tgt,
    unsigned int* __restrict__ ghist, int n)
{
    __shared__ unsigned int lhist[HIST_BINS];   // 8 KB

    uint4* lh4 = (uint4*)lhist;
    for (int b = threadIdx.x; b < HIST_BINS / 4; b += 256)
        lh4[b] = make_uint4(0u, 0u, 0u, 0u);
    __syncthreads();

    const int tid    = blockIdx.x * blockDim.x + threadIdx.x;
    const int stride = gridDim.x * blockDim.x;
    const int n4     = n >> 2;

    const float4* p4 = (const float4*)pred;
    const int4*   t4 = (const int4*)tgt;

    for (int i = tid; i < n4; i += stride) {
        float4 x = p4[i];
        int4   t = t4[i];
        float xs[4] = {x.x, x.y, x.z, x.w};
        int   ts[4] = {t.x, t.y, t.z, t.w};
#pragma unroll
        for (int c = 0; c < 4; ++c) {
            unsigned int u = __float_as_uint(xs[c]);
            int          m = (int)u >> 31;
            unsigned int key = u ^ (0x80000000u | (unsigned int)m);
            atomicAdd(&lhist[key >> KEY_SHIFT], ts[c] ? 65536u : 1u);
        }
    }
    for (int i = (n4 << 2) + tid; i < n; i += stride) {
        unsigned int u = __float_as_uint(pred[i]);
        int          m = (int)u >> 31;
        unsigned int key = u ^ (0x80000000u | (unsigned int)m);
        atomicAdd(&lhist[key >> KEY_SHIFT], tgt[i] ? 65536u : 1u);
    }

    // flush into this block's partial histogram (rotated start)
    __syncthreads();
    unsigned int* gp = ghist + (blockIdx.x & (NPART - 1)) * HIST_BINS;
    const int nq  = HIST_BINS / 4;                 // 512
    const int rot = (blockIdx.x * 32) & (nq - 1);
    for (int i = threadIdx.x; i < nq; i += 256) {
        int b = (i + rot) & (nq - 1);
        uint4 v = lh4[b];
        if (v.x) atomicAdd(&gp[4 * b + 0], v.x);
        if (v.y) atomicAdd(&gp[4 * b + 1], v.y);
        if (v.z) atomicAdd(&gp[4 * b + 2], v.z);
        if (v.w) atomicAdd(&gp[4 * b + 3], v.w);
    }
}

// ---------------------------------------------------------------------------
// Pass 2 (single block, 256 threads): each thread owns an 8-bin chunk; sums
// the NPART partials UNPACKED, Hillis-Steele scan for the descending positive
// prefix, then the bin-wise pAUC sum:
//   contribution = ng * E_f~U(0,1)[ max(0, (CP - 0.95P) + p*f) ]
// pAUC = S/(P*Ng);  loss = 0.5*CE_mean + 0.5*(1 - clip(pAUC/0.1,0,1)^2)
// ---------------------------------------------------------------------------
__global__ __launch_bounds__(256) void pass2_kernel(
    const unsigned int* __restrict__ hist, const double* __restrict__ ce_sum,
    const unsigned int* __restrict__ pos_cnt, float* __restrict__ out, int n)
{
    __shared__ double chunk_pos[256];
    __shared__ double sred[256];

    const int tid = threadIdx.x;
    const int lo  = HIST_BINS - (tid + 1) * 8;    // thread's 8-bin chunk

    unsigned int pos[8] = {0,0,0,0,0,0,0,0};
    unsigned int neg[8] = {0,0,0,0,0,0,0,0};
    const uint4* h4 = (const uint4*)hist;
#pragma unroll
    for (int p = 0; p < NPART; ++p) {
#pragma unroll
        for (int j = 0; j < 2; ++j) {
            uint4 v = h4[p * (HIST_BINS / 4) + lo / 4 + j];
            pos[4*j+0] += v.x >> 16;  neg[4*j+0] += v.x & 0xFFFFu;
            pos[4*j+1] += v.y >> 16;  neg[4*j+1] += v.y & 0xFFFFu;
            pos[4*j+2] += v.z >> 16;  neg[4*j+2] += v.z & 0xFFFFu;
            pos[4*j+3] += v.w >> 16;  neg[4*j+3] += v.w & 0xFFFFu;
        }
    }

    double psum = 0.0;
#pragma unroll
    for (int i = 0; i < 8; ++i) psum += (double)pos[i];
    chunk_pos[tid] = psum;
    __syncthreads();

    double v = psum;
    for (int s = 1; s < 256; s <<= 1) {
        double add = (tid >= s) ? chunk_pos[tid - s] : 0.0;
        __syncthreads();
        v += add;
        chunk_pos[tid] = v;
        __syncthreads();
    }
    double CP = v - psum;   // positives strictly above this chunk

    const unsigned int P = *pos_cnt;
    const double T = RECALL_LO_C * (double)P;

    double S = 0.0;
#pragma unroll
    for (int i = 7; i >= 0; --i) {
        double p  = (double)pos[i];
        double ng = (double)neg[i];
        if (ng > 0.0) {
            double a = CP - T;
            double contrib;
            if (a >= 0.0) {
                contrib = a + 0.5 * p;
            } else {
                double ac = a + p;
                contrib = (ac > 0.0 && p > 0.0) ? (ac * ac) / (2.0 * p) : 0.0;
            }
            S += ng * contrib;
        }
        CP += p;
    }
    sred[tid] = S;
    __syncthreads();
    for (int s = 128; s > 0; s >>= 1) {
        if (tid < s) sred[tid] += sred[tid + s];
        __syncthreads();
    }

    if (tid == 0) {
        double Ng = (double)n - (double)P;
        double pauc = 0.0;
        if (P > 0 && Ng > 0.0) pauc = sred[0] / ((double)P * Ng);
        double avg = pauc / (2.0 * (1.0 - RECALL_LO_C));   // pauc / 0.1
        avg = fmin(fmax(avg, 0.0), 1.0);
        double ce = *ce_sum / (double)n;
        out[0] = (float)(0.5 * ce + 0.5 * (1.0 - avg * avg));
    }
}

extern "C" void kernel_launch(void* const* d_in, const int* in_sizes, int n_in,
                              void* d_out, int out_size, void* d_ws, size_t ws_size,
                              hipStream_t stream)
{
    const float* pred = (const float*)d_in[0];
    const int*   tgt  = (const int*)d_in[1];
    const int n = in_sizes[0];  // predictions is (N,1) -> N elements

    unsigned int* ghist   = (unsigned int*)d_ws;                        // NPART x HIST_BINS
    double*       ce_sum  = (double*)((char*)d_ws + NPART * HIST_BYTES);
    unsigned int* pos_cnt = (unsigned int*)((char*)d_ws + NPART * HIST_BYTES + 8);

    hipMemsetAsync(d_ws, 0, NPART * HIST_BYTES + 16, stream);

    ce_kernel<<<GRID_CE, 256, 0, stream>>>(pred, tgt, ce_sum, pos_cnt, n);
    hist_kernel<<<GRID_HIST, 256, 0, stream>>>(pred, tgt, ghist, n);
    pass2_kernel<<<1, 256, 0, stream>>>(ghist, ce_sum, pos_cnt, (float*)d_out, n);
}